// Round 9
// baseline (181.745 us; speedup 1.0000x reference)
//
#include <hip/hip_runtime.h>
#include <math.h>
#include <stdint.h>

#define PI_F 3.14159265358979323846f
#define HALF_PI_F 1.57079632679489662f

// Problem constants: B=32, N=200000, H=1024, W=2048
#define IMG_H 1024
#define IMG_W 2048
#define NB 8    // batches per thread

// Workspace layout:
//   floats [0, 352)   : Rm (288) | sums (32) | cnts (32)
//   bytes  [2048, +16MB): FULLY-OVERLAPPING 2x2 RGB565 u64 image:
//     vo[y*W + x] = {p(y,x), p(y,x+1c), p(y+1c,x), p(y+1c,x+1c)} as 4x16-bit
//     (c = clamped to image bounds). One aligned 8B load = whole bilinear
//     footprint.
//
// Session ledger:
//   r1-r3: phase-split/fence attempts -> compiler re-fuses; bsl_main ~67-70us.
//          r2's real win: image 8MB->4MB (FETCH 184->27MB). BUT r0==r2 time
//          proved bandwidth/residency was NOT the wall.
//   r4-r5: asm-forced gather MLP -> RA collapse -> scratch: ABANDONED.
//   r4/r6: fused finalize (per-block threadfence) poisons L2: ABANDONED.
//   r8: launch_bounds (256,8) -> VGPR capped 32 -> spill (WRITE 3.3MB), 73us.
//       Occupancy barely moved (53->57) -> occupancy was never the limiter.
//   r9: diagnosis = gather-INSTRUCTION-throughput bound (2 divergent gathers
//       per sample, ~64 TA-cyc each ~= 42us floor ~= observed 67us).
//       Lever: 1 aligned u64 gather/sample via 16MB overlapping 2x2 texture.
//       L2-miss traffic is free per r0 evidence (L3 absorbs).

__device__ __forceinline__ float fast_atan2f(float y, float x) {
    float ax = fabsf(x), ay = fabsf(y);
    float mx = fmaxf(ax, ay), mn = fminf(ax, ay);
    float a = __fdividef(mn, mx);
    float s = a * a;
    float r = fmaf(s, -0.01172120f, 0.05265332f);
    r = fmaf(s, r, -0.11643287f);
    r = fmaf(s, r, 0.19354346f);
    r = fmaf(s, r, -0.33262347f);
    r = fmaf(s, r, 0.99997726f);
    r = r * a;
    if (ay > ax) r = HALF_PI_F - r;
    if (x < 0.0f) r = PI_F - r;
    return copysignf(r, y);
}

__device__ __forceinline__ uint32_t q565(float r, float g, float b) {
    uint32_t r5 = min((uint32_t)__float2uint_rn(r * 31.0f), 31u);
    uint32_t g6 = min((uint32_t)__float2uint_rn(g * 63.0f), 63u);
    uint32_t b5 = min((uint32_t)__float2uint_rn(b * 31.0f), 31u);
    return (r5 << 11) | (g6 << 5) | b5;
}

// Pack f32 HWC image -> overlapping 2x2 RGB565 u64 words.
// One block per row y: stage rows y and min(y+1,1023) to LDS (coalesced
// float4), each thread builds 8 adjacent u64 words (sharing 9 q565 per row).
__global__ __launch_bounds__(256) void bsl_pack_setup(
        const float* __restrict__ img, uint64_t* __restrict__ vo,
        const float* __restrict__ yaw, const float* __restrict__ pitch,
        const float* __restrict__ roll, float* __restrict__ rm,
        float* __restrict__ sums, float* __restrict__ cnts, int B) {
    __shared__ float lds[2][IMG_W * 3];     // 2 rows * 24 KB
    const int y = blockIdx.x;               // 0..1023
    const int tid = threadIdx.x;

    if (y == 0 && tid < 32) {
        int b = tid;
        if (b < B) {
            float cr = cosf(roll[b]),  sr = sinf(roll[b]);
            float cp = cosf(pitch[b]), sp = sinf(pitch[b]);
            float cy = cosf(yaw[b]),   sy = sinf(yaw[b]);
            float RX[9] = {1.f, 0.f, 0.f,   0.f, cr, -sr,   0.f, sr,  cr};
            float RY[9] = {cp,  0.f, sp,    0.f, 1.f, 0.f,  -sp, 0.f, cp};
            float RZ[9] = {cy, -sy, 0.f,    sy,  cy, 0.f,   0.f, 0.f, 1.f};
            float A[9], M[9];
            for (int i = 0; i < 3; ++i)
                for (int j = 0; j < 3; ++j) {
                    float s = 0.f;
                    for (int k = 0; k < 3; ++k) s += RZ[i*3+k] * RY[k*3+j];
                    A[i*3+j] = s;
                }
            for (int i = 0; i < 3; ++i)
                for (int j = 0; j < 3; ++j) {
                    float s = 0.f;
                    for (int k = 0; k < 3; ++k) s += A[i*3+k] * RX[k*3+j];
                    M[i*3+j] = s;
                }
            for (int k = 0; k < 9; ++k) rm[b*9+k] = M[k];
            sums[b] = 0.f;
            cnts[b] = 0.f;
        }
    }

    const int y1 = min(y + 1, IMG_H - 1);
    const float4* s0 = (const float4*)(img + (size_t)y  * IMG_W * 3);
    const float4* s1 = (const float4*)(img + (size_t)y1 * IMG_W * 3);
    float4* d0 = (float4*)lds[0];
    float4* d1 = (float4*)lds[1];
    #pragma unroll
    for (int i = 0; i < 6; ++i) {
        d0[tid + 256 * i] = s0[tid + 256 * i];
        d1[tid + 256 * i] = s1[tid + 256 * i];
    }
    __syncthreads();

    const int xb = tid * 8;
    uint32_t pa[9], pb[9];
    #pragma unroll
    for (int j = 0; j < 9; ++j) {
        int x = min(xb + j, IMG_W - 1);     // clamp col (x+1 at right edge)
        int x3 = x * 3;
        pa[j] = q565(lds[0][x3], lds[0][x3+1], lds[0][x3+2]);
        pb[j] = q565(lds[1][x3], lds[1][x3+1], lds[1][x3+2]);
    }
    uint64_t w[8];
    #pragma unroll
    for (int j = 0; j < 8; ++j) {
        w[j] = (uint64_t)(pa[j] | (pa[j+1] << 16))
             | ((uint64_t)(pb[j] | (pb[j+1] << 16)) << 32);
    }
    uint4* dst = (uint4*)(vo + ((size_t)y * IMG_W + xb));   // 64B/thread
    dst[0] = make_uint4((uint32_t)w[0], (uint32_t)(w[0] >> 32),
                        (uint32_t)w[1], (uint32_t)(w[1] >> 32));
    dst[1] = make_uint4((uint32_t)w[2], (uint32_t)(w[2] >> 32),
                        (uint32_t)w[3], (uint32_t)(w[3] >> 32));
    dst[2] = make_uint4((uint32_t)w[4], (uint32_t)(w[4] >> 32),
                        (uint32_t)w[5], (uint32_t)(w[5] >> 32));
    dst[3] = make_uint4((uint32_t)w[6], (uint32_t)(w[6] >> 32),
                        (uint32_t)w[7], (uint32_t)(w[7] >> 32));
}

// r9 main kernel: ONE aligned u64 gather per (point, batch) sample.
__global__ __launch_bounds__(256, 4) void bsl_main(
        const float* __restrict__ xyz,
        const float* __restrict__ rgb,
        const uint64_t* __restrict__ vo,
        const float* __restrict__ trans,
        const float* __restrict__ rm,
        float* __restrict__ sums,
        float* __restrict__ cnts,
        int n_pts) {
    const int b0 = blockIdx.y * NB;
    const int tid = threadIdx.x;
    const int n = blockIdx.x * 256 + tid;

    float accs[NB], cnl[NB];
    #pragma unroll
    for (int nb = 0; nb < NB; ++nb) { accs[nb] = 0.f; cnl[nb] = 0.f; }

    if (n < n_pts) {
        // nontemporal: don't let the point streams evict the image from L2
        float px = __builtin_nontemporal_load(&xyz[3*n+0]);
        float py = __builtin_nontemporal_load(&xyz[3*n+1]);
        float pz = __builtin_nontemporal_load(&xyz[3*n+2]);
        float r0 = __builtin_nontemporal_load(&rgb[3*n+0]);
        float r1 = __builtin_nontemporal_load(&rgb[3*n+1]);
        float r2 = __builtin_nontemporal_load(&rgb[3*n+2]);

        #pragma unroll
        for (int nb = 0; nb < NB; ++nb) {
            const int b = b0 + nb;
            const float* R = rm + b * 9;        // block-uniform -> s_load
            const float* T = trans + b * 3;
            float qx = px - T[0], qy = py - T[1], qz = pz - T[2];

            float vx = R[0]*qx + R[1]*qy + R[2]*qz;
            float vy = R[3]*qx + R[4]*qy + R[5]*qz;
            float vz = R[6]*qx + R[7]*qy + R[8]*qz;

            float rxy   = sqrtf(vx*vx + vy*vy);
            float theta = fast_atan2f(rxy, vz);     // [0, pi]
            float praw  = fast_atan2f(vy, vx);      // (-pi, pi]

            // xf = 1023.5 - 1024*praw/pi ; yf = 1024*theta/pi - 0.5
            float xf = fmaf(praw,  -325.949323452f, 1023.5f);
            float yf = fmaf(theta,  325.949323452f, -0.5f);

            float x0f = floorf(xf), y0f = floorf(yf);
            float wx = xf - x0f,    wy = yf - y0f;

            // x0 in [-1,2047], y0 in [-1,1023]; clamp base for the load.
            float xbf = fminf(fmaxf(x0f, 0.0f), 2047.0f);
            float ybf = fminf(fmaxf(y0f, 0.0f), 1023.0f);
            int xb = (int)xbf;
            int yb = (int)ybf;

            // ONE 8B-aligned gather: whole 2x2 footprint.
            uint64_t wq = vo[((size_t)yb << 11) + xb];
            uint32_t lo = (uint32_t)wq;             // row y0 : cols x0, x1
            uint32_t hi = (uint32_t)(wq >> 32);     // row y1 : cols x0, x1

            bool vx0 = (x0f >= 0.0f);       // x0 valid
            bool vx1 = (x0f <= 2046.0f);    // x1 valid
            bool vy0 = (y0f >= 0.0f);       // y0 valid
            bool vy1 = (y0f <= 1022.0f);    // y1 valid

            // y0==-1: base row 0 -> row y1's data is in lo.
            uint32_t row1 = vy0 ? hi : lo;
            // x0==-1: base col 0 -> col x1's data is in slot0.
            uint32_t t00 = lo & 0xffffu;
            uint32_t t10 = (vx0 ? (lo >> 16) : lo) & 0xffffu;
            uint32_t t01 = row1 & 0xffffu;
            uint32_t t11 = (vx0 ? (row1 >> 16) : row1) & 0xffffu;

            float omx = 1.0f - wx, omy = 1.0f - wy;
            float w00 = (vx0 & vy0) ? omx * omy : 0.0f;
            float w10 = (vx1 & vy0) ? wx  * omy : 0.0f;
            float w01 = (vx0 & vy1) ? omx * wy  : 0.0f;
            float w11 = (vx1 & vy1) ? wx  * wy  : 0.0f;

            // integer-valued float channels; fold 1/31,1/63 into the final fma
            float r00 = (float)(t00 >> 11),        r10 = (float)(t10 >> 11);
            float r01 = (float)(t01 >> 11),        r11 = (float)(t11 >> 11);
            float g00 = (float)((t00 >> 5) & 63u), g10 = (float)((t10 >> 5) & 63u);
            float g01 = (float)((t01 >> 5) & 63u), g11 = (float)((t11 >> 5) & 63u);
            float b00 = (float)(t00 & 31u),        b10 = (float)(t10 & 31u);
            float b01 = (float)(t01 & 31u),        b11 = (float)(t11 & 31u);

            float sr = r00*w00 + r10*w10 + r01*w01 + r11*w11;
            float sg = g00*w00 + g10*w10 + g01*w01 + g11*w11;
            float sb = b00*w00 + b10*w10 + b01*w01 + b11*w11;

            bool m = !((sr == 0.0f) && (sg == 0.0f) && (sb == 0.0f));

            float d0 = fmaf(sr, 1.0f / 31.0f, -r0);
            float d1 = fmaf(sg, 1.0f / 63.0f, -r1);
            float d2 = fmaf(sb, 1.0f / 31.0f, -r2);
            float per = sqrtf(d0*d0 + d1*d1 + d2*d2);

            accs[nb] += m ? per : 0.0f;
            cnl[nb]  += m ? 1.0f : 0.0f;
        }
    }

    // wave(64) shuffle reduce per batch, then LDS across 4 waves, then atomics
    __shared__ float lsum[4][NB], lcnt[4][NB];
    int wid = tid >> 6;
    int lane = tid & 63;
    #pragma unroll
    for (int nb = 0; nb < NB; ++nb) {
        float a = accs[nb], c = cnl[nb];
        #pragma unroll
        for (int off = 32; off > 0; off >>= 1) {
            a += __shfl_down(a, off, 64);
            c += __shfl_down(c, off, 64);
        }
        if (lane == 0) { lsum[wid][nb] = a; lcnt[wid][nb] = c; }
    }
    __syncthreads();
    if (tid < NB * 2) {
        int nb = tid & (NB - 1);
        int k = tid >> 3;   // 0 = sum, 1 = cnt
        float v = 0.f;
        #pragma unroll
        for (int w = 0; w < 4; ++w) v += k ? lcnt[w][nb] : lsum[w][nb];
        atomicAdd(k ? &cnts[b0 + nb] : &sums[b0 + nb], v);
    }
}

__global__ void bsl_finalize(const float* __restrict__ sums,
                             const float* __restrict__ cnts,
                             float* __restrict__ out,
                             int B) {
    int b = threadIdx.x;  // 0..63
    float loss = 0.f;
    if (b < B) {
        loss = sums[b] / cnts[b];
        out[1 + b] = loss;
    }
    #pragma unroll
    for (int off = 32; off > 0; off >>= 1)
        loss += __shfl_down(loss, off, 64);
    if (b == 0) out[0] = loss;
}

extern "C" void kernel_launch(void* const* d_in, const int* in_sizes, int n_in,
                              void* d_out, int out_size, void* d_ws, size_t ws_size,
                              hipStream_t stream) {
    const float* xyz   = (const float*)d_in[0];
    const float* rgb   = (const float*)d_in[1];
    const float* img   = (const float*)d_in[2];
    const float* trans = (const float*)d_in[3];
    const float* yaw   = (const float*)d_in[4];
    const float* pitch = (const float*)d_in[5];
    const float* roll  = (const float*)d_in[6];
    float* out = (float*)d_out;

    const int n_pts = in_sizes[0] / 3;      // 200000
    const int B     = in_sizes[3] / 3;      // 32

    float* ws   = (float*)d_ws;
    float* rm   = ws;               // 9*B floats
    float* sums = ws + 9 * B;       // B floats
    float* cnts = ws + 10 * B;      // B floats
    uint64_t* vo = (uint64_t*)((char*)d_ws + 2048);  // 16 MB

    bsl_pack_setup<<<IMG_H, 256, 0, stream>>>(
        img, vo, yaw, pitch, roll, rm, sums, cnts, B);

    dim3 grid((n_pts + 255) / 256, B / NB);
    bsl_main<<<grid, 256, 0, stream>>>(xyz, rgb, vo, trans, rm, sums, cnts, n_pts);

    bsl_finalize<<<1, 64, 0, stream>>>(sums, cnts, out, B);
}

// Round 10
// 149.438 us; speedup vs baseline: 1.2162x; 1.2162x over previous
//
#include <hip/hip_runtime.h>
#include <math.h>
#include <stdint.h>

#define PI_F 3.14159265358979323846f
#define HALF_PI_F 1.57079632679489662f

// Problem constants: B=32, N=200000, H=1024, W=2048
#define IMG_H 1024
#define IMG_W 2048
#define NB 8    // batches per thread

// Workspace layout:
//   floats [0, 352)   : Rm (288) | sums (32) | cnts (32)
//   bytes  [2048, +4MB): NON-overlapping even/odd row-pair RGB565 image:
//     u32 vp2[(y>>1)*W + x] = lo: pix(2k, x), hi: pix(2k+1, x)
//
// Session ledger:
//   r1-r3: phase-split/fence attempts -> compiler keeps ~2 gathers in flight
//          regardless; bsl_main ~67-70us. r2: image 8MB->4MB, FETCH 184->27MB.
//   r4-r5: asm-forced gather MLP -> RA collapse -> scratch: ABANDONED.
//   r4/r6: fused finalize (per-block threadfence) poisons L2: ABANDONED.
//   r8: launch_bounds(256,8) -> VGPR forced 32 < natural 36 -> spill: revert.
//   r9: 1 u64 gather via 16MB texture -> L2 blown (FETCH 291MB), 91us.
//       MODEL (survives all rounds): latency-bound; time ~ requests /
//       (waves/CU x ~2-4 inflight / ~200cyc L2-hit). Image MUST stay 4MB.
//   r10: TLP without spills: trim xfa (flag-packing, r4 layout, verified) +
//        launch_bounds(256,6) = 24 waves/CU, VGPR cap ~42 > demand ~36.

// 8-byte pair of adjacent vp2 words, 4-byte aligned.
struct __attribute__((packed, aligned(4))) U2 { uint32_t a, b; };

__device__ __forceinline__ float fast_atan2f(float y, float x) {
    float ax = fabsf(x), ay = fabsf(y);
    float mx = fmaxf(ax, ay), mn = fminf(ax, ay);
    float a = __fdividef(mn, mx);
    float s = a * a;
    float r = fmaf(s, -0.01172120f, 0.05265332f);
    r = fmaf(s, r, -0.11643287f);
    r = fmaf(s, r, 0.19354346f);
    r = fmaf(s, r, -0.33262347f);
    r = fmaf(s, r, 0.99997726f);
    r = r * a;
    if (ay > ax) r = HALF_PI_F - r;
    if (x < 0.0f) r = PI_F - r;
    return copysignf(r, y);
}

__device__ __forceinline__ uint32_t q565(float r, float g, float b) {
    uint32_t r5 = min((uint32_t)__float2uint_rn(r * 31.0f), 31u);
    uint32_t g6 = min((uint32_t)__float2uint_rn(g * 63.0f), 63u);
    uint32_t b5 = min((uint32_t)__float2uint_rn(b * 31.0f), 31u);
    return (r5 << 11) | (g6 << 5) | b5;
}

// Pack f32 HWC image -> even/odd row-pair RGB565 u32.
// One block per row-pair; coalesced float4 loads -> 48 KB LDS -> each thread
// packs 8 adjacent output words (2x uint4 stores). Block 0 also does setup.
__global__ __launch_bounds__(256) void bsl_pack_setup(
        const float* __restrict__ img, uint32_t* __restrict__ vp2,
        const float* __restrict__ yaw, const float* __restrict__ pitch,
        const float* __restrict__ roll, float* __restrict__ rm,
        float* __restrict__ sums, float* __restrict__ cnts, int B) {
    __shared__ float lds[2][IMG_W * 3];     // 2 rows * 24 KB
    const int y2 = blockIdx.x;              // 0..511
    const int tid = threadIdx.x;

    if (y2 == 0 && tid < 32) {
        int b = tid;
        if (b < B) {
            float cr = cosf(roll[b]),  sr = sinf(roll[b]);
            float cp = cosf(pitch[b]), sp = sinf(pitch[b]);
            float cy = cosf(yaw[b]),   sy = sinf(yaw[b]);
            float RX[9] = {1.f, 0.f, 0.f,   0.f, cr, -sr,   0.f, sr,  cr};
            float RY[9] = {cp,  0.f, sp,    0.f, 1.f, 0.f,  -sp, 0.f, cp};
            float RZ[9] = {cy, -sy, 0.f,    sy,  cy, 0.f,   0.f, 0.f, 1.f};
            float A[9], M[9];
            for (int i = 0; i < 3; ++i)
                for (int j = 0; j < 3; ++j) {
                    float s = 0.f;
                    for (int k = 0; k < 3; ++k) s += RZ[i*3+k] * RY[k*3+j];
                    A[i*3+j] = s;
                }
            for (int i = 0; i < 3; ++i)
                for (int j = 0; j < 3; ++j) {
                    float s = 0.f;
                    for (int k = 0; k < 3; ++k) s += A[i*3+k] * RX[k*3+j];
                    M[i*3+j] = s;
                }
            for (int k = 0; k < 9; ++k) rm[b*9+k] = M[k];
            sums[b] = 0.f;
            cnts[b] = 0.f;
        }
    }

    // Stage rows 2*y2 and 2*y2+1 (1536 float4 each), fully coalesced.
    const float4* s0 = (const float4*)(img + (size_t)(2 * y2)     * IMG_W * 3);
    const float4* s1 = (const float4*)(img + (size_t)(2 * y2 + 1) * IMG_W * 3);
    float4* d0 = (float4*)lds[0];
    float4* d1 = (float4*)lds[1];
    #pragma unroll
    for (int i = 0; i < 6; ++i) {
        d0[tid + 256 * i] = s0[tid + 256 * i];
        d1[tid + 256 * i] = s1[tid + 256 * i];
    }
    __syncthreads();

    // Each thread packs 8 adjacent columns.
    const int xb = tid * 8;
    uint32_t w[8];
    #pragma unroll
    for (int j = 0; j < 8; ++j) {
        int x3 = (xb + j) * 3;
        uint32_t lo = q565(lds[0][x3], lds[0][x3+1], lds[0][x3+2]);
        uint32_t hi = q565(lds[1][x3], lds[1][x3+1], lds[1][x3+2]);
        w[j] = lo | (hi << 16);
    }
    uint4* dst = (uint4*)(vp2 + ((size_t)y2 * IMG_W + xb));
    dst[0] = make_uint4(w[0], w[1], w[2], w[3]);
    dst[1] = make_uint4(w[4], w[5], w[6], w[7]);
}

// r10 main: r3 structure, xfa removed (flags packed in shp, r4 layout),
// launch_bounds (256,6): 24 waves/CU, VGPR cap ~42 > natural demand ~36.
__global__ __launch_bounds__(256, 6) void bsl_main(
        const float* __restrict__ xyz,
        const float* __restrict__ rgb,
        const uint32_t* __restrict__ vp2,
        const float* __restrict__ trans,
        const float* __restrict__ rm,
        float* __restrict__ sums,
        float* __restrict__ cnts,
        int n_pts) {
    const int b0 = blockIdx.y * NB;
    const int tid = threadIdx.x;
    const int n = blockIdx.x * 256 + tid;

    float accs[NB], cnl[NB];
    #pragma unroll
    for (int nb = 0; nb < NB; ++nb) { accs[nb] = 0.f; cnl[nb] = 0.f; }

    if (n < n_pts) {
        // nontemporal: don't let the point streams evict the image from L2
        float px = __builtin_nontemporal_load(&xyz[3*n+0]);
        float py = __builtin_nontemporal_load(&xyz[3*n+1]);
        float pz = __builtin_nontemporal_load(&xyz[3*n+2]);
        float r0 = __builtin_nontemporal_load(&rgb[3*n+0]);
        float r1 = __builtin_nontemporal_load(&rgb[3*n+1]);
        float r2 = __builtin_nontemporal_load(&rgb[3*n+2]);

        // Phase 1: coords + flags + pair loads for all NB batches.
        float wxa[NB], wya[NB];
        uint32_t shp[NB];
        uint32_t pAa[NB], pAb[NB], pBa[NB], pBb[NB];
        #pragma unroll
        for (int nb = 0; nb < NB; ++nb) {
            const int b = b0 + nb;
            const float* R = rm + b * 9;        // block-uniform -> s_load
            const float* T = trans + b * 3;
            float qx = px - T[0], qy = py - T[1], qz = pz - T[2];

            float vx = R[0]*qx + R[1]*qy + R[2]*qz;
            float vy = R[3]*qx + R[4]*qy + R[5]*qz;
            float vz = R[6]*qx + R[7]*qy + R[8]*qz;

            float rxy   = sqrtf(vx*vx + vy*vy);
            float theta = fast_atan2f(rxy, vz);     // [0, pi]
            float praw  = fast_atan2f(vy, vx);      // (-pi, pi]

            // xf = 1023.5 - 1024*praw/pi ; yf = 1024*theta/pi - 0.5
            float xf = fmaf(praw,  -325.949323452f, 1023.5f);
            float yf = fmaf(theta,  325.949323452f, -0.5f);

            float x0f = floorf(xf);
            float y0f = floorf(yf);
            wxa[nb] = xf - x0f;
            wya[nb] = yf - y0f;

            // base column clamped to [0,2046] so pair (xb, xb+1) is in-bounds
            float xbf  = fminf(fmaxf(x0f, 0.0f), 2046.0f);
            float yb0f = fminf(fmaxf(y0f,        0.0f), 1023.0f);
            float yb1f = fminf(fmaxf(y0f + 1.0f, 0.0f), 1023.0f);
            int xb  = (int)xbf;
            int y0c = (int)yb0f;
            int y1c = (int)yb1f;

            // packed per-sample flags (r4 layout, verified r4/r5):
            // b0: y0 parity, b1: y1 parity, b2: vy0, b3: vy1,
            // b4: vx0, b5: vx1, b6: xhi (x0f >= 2047)
            uint32_t sp = (uint32_t)(y0c & 1) | ((uint32_t)(y1c & 1) << 1);
            if (y0f >= 0.0f)     sp |= 4u;
            if (y0f <= 1022.0f)  sp |= 8u;
            if (x0f >= 0.0f)     sp |= 16u;
            if (x0f <= 2046.0f)  sp |= 32u;
            if (x0f >= 2047.0f)  sp |= 64u;
            shp[nb] = sp;

            // row-pair words: vp2[(y>>1)*2048 + xb], cols xb, xb+1
            U2 tA = *(const U2*)(vp2 + (((y0c >> 1) << 11) + xb));
            U2 tB = *(const U2*)(vp2 + (((y1c >> 1) << 11) + xb));
            pAa[nb] = tA.a; pAb[nb] = tA.b;
            pBa[nb] = tB.a; pBb[nb] = tB.b;
        }

        #pragma unroll
        for (int nb = 0; nb < NB; ++nb) {
            asm volatile("" : "+v"(pAa[nb]), "+v"(pAb[nb]),
                             "+v"(pBa[nb]), "+v"(pBb[nb]) :: "memory");
        }

        // Phase 2: decode + blend + accumulate (flag-driven, no floorf).
        #pragma unroll
        for (int nb = 0; nb < NB; ++nb) {
            uint32_t sp = shp[nb];
            float wx = wxa[nb], wy = wya[nb];

            bool vy0 = (sp & 4u)  != 0u;
            bool vy1 = (sp & 8u)  != 0u;
            bool vx0 = (sp & 16u) != 0u;
            bool vx1 = (sp & 32u) != 0u;
            bool xhi = (sp & 64u) != 0u;

            float omx = 1.0f - wx, omy = 1.0f - wy;
            float w00 = (vx0 & vy0) ? omx * omy : 0.0f;
            float w10 = (vx1 & vy0) ? wx  * omy : 0.0f;
            float w01 = (vx0 & vy1) ? omx * wy  : 0.0f;
            float w11 = (vx1 & vy1) ? wx  * wy  : 0.0f;

            uint32_t sh0 = (sp & 1u) << 4;      // row-parity half-select
            uint32_t sh1 = (sp & 2u) << 3;

            // column fixups:
            // x0==2047: base clamped to 2046 -> col x0 is .b (x1 weights are 0)
            // x0==-1:   base 0 -> col x1 is .a (x0 weights are 0)
            uint32_t A0 = xhi ? pAb[nb] : pAa[nb];    // (y0 row-pair, col x0)
            uint32_t A1 = vx0 ? pAb[nb] : pAa[nb];    // (y0 row-pair, col x1)
            uint32_t B0 = xhi ? pBb[nb] : pBa[nb];    // (y1 row-pair, col x0)
            uint32_t B1 = vx0 ? pBb[nb] : pBa[nb];    // (y1 row-pair, col x1)

            uint32_t t00 = (A0 >> sh0) & 0xffffu;
            uint32_t t10 = (A1 >> sh0) & 0xffffu;
            uint32_t t01 = (B0 >> sh1) & 0xffffu;
            uint32_t t11 = (B1 >> sh1) & 0xffffu;

            // integer-valued float channels; fold 1/31,1/63 into the final fma
            float r00 = (float)(t00 >> 11),        r10 = (float)(t10 >> 11);
            float r01 = (float)(t01 >> 11),        r11 = (float)(t11 >> 11);
            float g00 = (float)((t00 >> 5) & 63u), g10 = (float)((t10 >> 5) & 63u);
            float g01 = (float)((t01 >> 5) & 63u), g11 = (float)((t11 >> 5) & 63u);
            float b00 = (float)(t00 & 31u),        b10 = (float)(t10 & 31u);
            float b01 = (float)(t01 & 31u),        b11 = (float)(t11 & 31u);

            float sr = r00*w00 + r10*w10 + r01*w01 + r11*w11;
            float sg = g00*w00 + g10*w10 + g01*w01 + g11*w11;
            float sb = b00*w00 + b10*w10 + b01*w01 + b11*w11;

            bool m = !((sr == 0.0f) && (sg == 0.0f) && (sb == 0.0f));

            float d0 = fmaf(sr, 1.0f / 31.0f, -r0);
            float d1 = fmaf(sg, 1.0f / 63.0f, -r1);
            float d2 = fmaf(sb, 1.0f / 31.0f, -r2);
            float per = sqrtf(d0*d0 + d1*d1 + d2*d2);

            accs[nb] += m ? per : 0.0f;
            cnl[nb]  += m ? 1.0f : 0.0f;
        }
    }

    // wave(64) shuffle reduce per batch, then LDS across 4 waves, then atomics
    __shared__ float lsum[4][NB], lcnt[4][NB];
    int wid = tid >> 6;
    int lane = tid & 63;
    #pragma unroll
    for (int nb = 0; nb < NB; ++nb) {
        float a = accs[nb], c = cnl[nb];
        #pragma unroll
        for (int off = 32; off > 0; off >>= 1) {
            a += __shfl_down(a, off, 64);
            c += __shfl_down(c, off, 64);
        }
        if (lane == 0) { lsum[wid][nb] = a; lcnt[wid][nb] = c; }
    }
    __syncthreads();
    if (tid < NB * 2) {
        int nb = tid & (NB - 1);
        int k = tid >> 3;   // 0 = sum, 1 = cnt
        float v = 0.f;
        #pragma unroll
        for (int w = 0; w < 4; ++w) v += k ? lcnt[w][nb] : lsum[w][nb];
        atomicAdd(k ? &cnts[b0 + nb] : &sums[b0 + nb], v);
    }
}

__global__ void bsl_finalize(const float* __restrict__ sums,
                             const float* __restrict__ cnts,
                             float* __restrict__ out,
                             int B) {
    int b = threadIdx.x;  // 0..63
    float loss = 0.f;
    if (b < B) {
        loss = sums[b] / cnts[b];
        out[1 + b] = loss;
    }
    #pragma unroll
    for (int off = 32; off > 0; off >>= 1)
        loss += __shfl_down(loss, off, 64);
    if (b == 0) out[0] = loss;
}

extern "C" void kernel_launch(void* const* d_in, const int* in_sizes, int n_in,
                              void* d_out, int out_size, void* d_ws, size_t ws_size,
                              hipStream_t stream) {
    const float* xyz   = (const float*)d_in[0];
    const float* rgb   = (const float*)d_in[1];
    const float* img   = (const float*)d_in[2];
    const float* trans = (const float*)d_in[3];
    const float* yaw   = (const float*)d_in[4];
    const float* pitch = (const float*)d_in[5];
    const float* roll  = (const float*)d_in[6];
    float* out = (float*)d_out;

    const int n_pts = in_sizes[0] / 3;      // 200000
    const int B     = in_sizes[3] / 3;      // 32

    float* ws   = (float*)d_ws;
    float* rm   = ws;               // 9*B floats
    float* sums = ws + 9 * B;       // B floats
    float* cnts = ws + 10 * B;      // B floats
    uint32_t* vp2 = (uint32_t*)((char*)d_ws + 2048);  // 4 MB

    bsl_pack_setup<<<IMG_H / 2, 256, 0, stream>>>(
        img, vp2, yaw, pitch, roll, rm, sums, cnts, B);

    dim3 grid((n_pts + 255) / 256, B / NB);
    bsl_main<<<grid, 256, 0, stream>>>(xyz, rgb, vp2, trans, rm, sums, cnts, n_pts);

    bsl_finalize<<<1, 64, 0, stream>>>(sums, cnts, out, B);
}